// Round 1
// baseline (404.221 us; speedup 1.0000x reference)
//
#include <hip/hip_runtime.h>
#include <hip/hip_bf16.h>

#define B_SZ   4096
#define F_DIM  64
#define H_DIM  128

typedef short bf16x8 __attribute__((ext_vector_type(8)));
typedef float f32x4  __attribute__((ext_vector_type(4)));

__device__ __forceinline__ short f2bf(float f) {
    __hip_bfloat16 h = __float2bfloat16(f);
    return *reinterpret_cast<short*>(&h);
}
__device__ __forceinline__ float bf2f(unsigned short u) {
    unsigned int x = ((unsigned int)u) << 16;
    float f;
    __builtin_memcpy(&f, &x, 4);
    return f;
}
__device__ __forceinline__ float fsig(float x) {
    return __builtin_amdgcn_rcpf(1.0f + __expf(-x));
}
__device__ __forceinline__ float ftanhf(float x) {
    return 1.0f - 2.0f * __builtin_amdgcn_rcpf(__expf(2.0f * x) + 1.0f);
}
// XOR swizzle: row-major [64][128] bf16 tile, stride 256 B; spreads banks (G4 fix)
__device__ __forceinline__ int swz(int row, int cbyte) {
    return row * 256 + (cbyte ^ ((row & 7) << 4));
}

// ---------------------------------------------------------------------------
// Kernel 0: weights fp32 -> bf16
__global__ void prep_kernel(const float* __restrict__ wih, const float* __restrict__ whh,
                            short* __restrict__ wihb, short* __restrict__ whhb) {
    int i = blockIdx.x * 256 + threadIdx.x;
    if (i < 384 * 128) {
        wihb[i] = f2bf(wih[i]);
        whhb[i] = f2bf(whh[i]);
    }
}

// ---------------------------------------------------------------------------
// Kernel 1: fused feature-build + GRU (bf16 MFMA) + masked mean aggregation.
// One block = 2 nodes = 64 rows (M=64), 8 waves. Wave w owns gate columns
// j in [16w, 16w+16) for all three gates (r,z,n) of both GEMMs (Gx, Gh).
__global__ __launch_bounds__(512, 2) void gru_agg_kernel(
    const int*   __restrict__ ngh_id,
    const int*   __restrict__ e_idx,
    const float* __restrict__ ngh_ts,
    const float* __restrict__ hidden_store,
    const float* __restrict__ e_feat,
    const float* __restrict__ basis_freq,
    const float* __restrict__ phase,
    const float* __restrict__ cut_time,
    const short* __restrict__ wihb,
    const short* __restrict__ whhb,
    const float* __restrict__ b_ih,
    const float* __restrict__ b_hh,
    float*       __restrict__ agg)
{
    __shared__ __align__(16) char sX[64 * 256];   // 64 rows x 128 bf16 (swizzled)
    __shared__ __align__(16) char sH[64 * 256];
    __shared__ float sMask[64];
    __shared__ float sInv[2];

    const int bid = blockIdx.x;
    const int tid = threadIdx.x;

    // ---- build X ([e_emb | ts_emb]) and H tiles in LDS (bf16, swizzled) ----
    {
        const int row   = tid >> 3;          // 0..63
        const int q     = tid & 7;           // 0..7 -> 16 columns each
        const int flat  = bid * 64 + row;    // row into (3B*K)
        const int rnode = bid * 2 + (row >> 5);

        if (q < 4) {                         // e_emb columns q*16 .. q*16+16
            const int c0 = q * 16;
            const int e  = e_idx[flat];
            const float4* src = reinterpret_cast<const float4*>(e_feat + (size_t)e * F_DIM + c0);
            float tmp[16];
            *reinterpret_cast<float4*>(tmp + 0)  = src[0];
            *reinterpret_cast<float4*>(tmp + 4)  = src[1];
            *reinterpret_cast<float4*>(tmp + 8)  = src[2];
            *reinterpret_cast<float4*>(tmp + 12) = src[3];
            union { bf16x8 v[2]; short s[16]; } u;
            #pragma unroll
            for (int i = 0; i < 16; ++i) u.s[i] = f2bf(tmp[i]);
            *reinterpret_cast<bf16x8*>(&sX[swz(row, c0 * 2)])      = u.v[0];
            *reinterpret_cast<bf16x8*>(&sX[swz(row, c0 * 2 + 16)]) = u.v[1];
        } else {                             // ts_emb columns 64+f0 .. +16
            const int f0 = (q - 4) * 16;
            const float dt = cut_time[rnode & (B_SZ - 1)] - ngh_ts[flat];
            union { bf16x8 v[2]; short s[16]; } u;
            #pragma unroll
            for (int i = 0; i < 16; ++i) {
                const int f = f0 + i;
                u.s[i] = f2bf(cosf(dt * basis_freq[f] + phase[f]));
            }
            *reinterpret_cast<bf16x8*>(&sX[swz(row, 128 + f0 * 2)])      = u.v[0];
            *reinterpret_cast<bf16x8*>(&sX[swz(row, 128 + f0 * 2 + 16)]) = u.v[1];
        }
        {                                    // H tile columns q*16 .. +16
            const int c0 = q * 16;
            const float4* src = reinterpret_cast<const float4*>(hidden_store + (size_t)flat * H_DIM + c0);
            float tmp[16];
            *reinterpret_cast<float4*>(tmp + 0)  = src[0];
            *reinterpret_cast<float4*>(tmp + 4)  = src[1];
            *reinterpret_cast<float4*>(tmp + 8)  = src[2];
            *reinterpret_cast<float4*>(tmp + 12) = src[3];
            union { bf16x8 v[2]; short s[16]; } u;
            #pragma unroll
            for (int i = 0; i < 16; ++i) u.s[i] = f2bf(tmp[i]);
            *reinterpret_cast<bf16x8*>(&sH[swz(row, c0 * 2)])      = u.v[0];
            *reinterpret_cast<bf16x8*>(&sH[swz(row, c0 * 2 + 16)]) = u.v[1];
        }
        if (tid < 64) {                      // mask + neighbor counts (wave 0)
            const int nid = ngh_id[bid * 64 + tid];
            sMask[tid] = (nid != 0) ? 1.0f : 0.0f;
            unsigned long long mb = __ballot(nid != 0);
            if (tid == 0) {
                int c0n = __popcll(mb & 0xFFFFFFFFull);
                int c1n = __popcll(mb >> 32);
                sInv[0] = 1.0f / (float)(c0n > 1 ? c0n : 1);
                sInv[1] = 1.0f / (float)(c1n > 1 ? c1n : 1);
            }
        }
    }
    __syncthreads();

    // ---- K-loop: Gx = X @ W_ih^T, Gh = H @ W_hh^T (K=128, 4 ksteps) ----
    const int lane = tid & 63;
    const int wv   = tid >> 6;           // 0..7
    const int j0   = wv * 16;
    const int jc   = j0 + (lane & 15);   // gate column this lane owns
    const int kh   = lane >> 4;          // 0..3 (k-halfword group)

    f32x4 accx[3][4], acch[3][4];
    #pragma unroll
    for (int g = 0; g < 3; ++g)
        #pragma unroll
        for (int mf = 0; mf < 4; ++mf) {
            accx[g][mf] = (f32x4){0.f, 0.f, 0.f, 0.f};
            acch[g][mf] = (f32x4){0.f, 0.f, 0.f, 0.f};
        }

    #pragma unroll
    for (int ks = 0; ks < 4; ++ks) {
        bf16x8 ax[4], ah[4];
        #pragma unroll
        for (int mf = 0; mf < 4; ++mf) {
            const int off = swz(mf * 16 + (lane & 15), ks * 64 + kh * 16);
            ax[mf] = *reinterpret_cast<const bf16x8*>(&sX[off]);
            ah[mf] = *reinterpret_cast<const bf16x8*>(&sH[off]);
        }
        #pragma unroll
        for (int g = 0; g < 3; ++g) {
            const int wrow = g * 128 + jc;
            bf16x8 bx = *reinterpret_cast<const bf16x8*>(wihb + wrow * 128 + ks * 32 + kh * 8);
            bf16x8 bh = *reinterpret_cast<const bf16x8*>(whhb + wrow * 128 + ks * 32 + kh * 8);
            #pragma unroll
            for (int mf = 0; mf < 4; ++mf) {
                accx[g][mf] = __builtin_amdgcn_mfma_f32_16x16x32_bf16(ax[mf], bx, accx[g][mf], 0, 0, 0);
                acch[g][mf] = __builtin_amdgcn_mfma_f32_16x16x32_bf16(ah[mf], bh, acch[g][mf], 0, 0, 0);
            }
        }
    }

    // ---- epilogue: gates, h_new, masked sum over K, mean ----
    const float bir = b_ih[jc],       bhr = b_hh[jc];
    const float biz = b_ih[128 + jc], bhz = b_hh[128 + jc];
    const float bin = b_ih[256 + jc], bhn = b_hh[256 + jc];

    float s0 = 0.f, s1 = 0.f;
    #pragma unroll
    for (int mf = 0; mf < 4; ++mf) {
        #pragma unroll
        for (int i = 0; i < 4; ++i) {
            const int row = mf * 16 + (lane >> 4) * 4 + i;   // C/D: col=lane&15, row=(lane>>4)*4+reg
            const float gr = accx[0][mf][i] + acch[0][mf][i] + bir + bhr;
            const float gz = accx[1][mf][i] + acch[1][mf][i] + biz + bhz;
            const float rr = fsig(gr);
            const float zz = fsig(gz);
            const float nn = ftanhf(accx[2][mf][i] + bin + rr * (acch[2][mf][i] + bhn));
            const float hc = bf2f(*reinterpret_cast<const unsigned short*>(&sH[swz(row, jc * 2)]));
            const float hv = ((1.0f - zz) * nn + zz * hc) * sMask[row];
            if (mf < 2) s0 += hv; else s1 += hv;
        }
    }
    s0 += __shfl_xor(s0, 16, 64);
    s0 += __shfl_xor(s0, 32, 64);
    s1 += __shfl_xor(s1, 16, 64);
    s1 += __shfl_xor(s1, 32, 64);
    if (lane < 16) {
        agg[(bid * 2 + 0) * H_DIM + jc] = s0 * sInv[0];
        agg[(bid * 2 + 1) * H_DIM + jc] = s1 * sInv[1];
    }
}

// ---------------------------------------------------------------------------
// Kernel 2: emb = relu([node_raw, agg] @ W_out^T + b_out), 3B x 64
__global__ __launch_bounds__(64) void emb_kernel(
    const int*   __restrict__ src_ids, const int* __restrict__ tgt_ids,
    const int*   __restrict__ bad_ids, const float* __restrict__ n_feat,
    const float* __restrict__ W_out,   const float* __restrict__ b_out,
    const float* __restrict__ agg,     float* __restrict__ emb)
{
    __shared__ float sv[192];
    const int node = blockIdx.x;
    const int j = threadIdx.x;                    // 0..63
    int id;
    if (node < B_SZ)            id = src_ids[node];
    else if (node < 2 * B_SZ)   id = tgt_ids[node - B_SZ];
    else                        id = bad_ids[node - 2 * B_SZ];
    sv[j]       = n_feat[(size_t)id * F_DIM + j];
    sv[64 + j]  = agg[node * H_DIM + j];
    sv[128 + j] = agg[node * H_DIM + 64 + j];
    __syncthreads();
    float acc = b_out[j];
    const float4* wr = reinterpret_cast<const float4*>(W_out + j * 192);
    #pragma unroll 8
    for (int c = 0; c < 48; ++c) {
        float4 w = wr[c];
        acc += w.x * sv[c * 4] + w.y * sv[c * 4 + 1] + w.z * sv[c * 4 + 2] + w.w * sv[c * 4 + 3];
    }
    emb[node * F_DIM + j] = fmaxf(acc, 0.0f);
}

// ---------------------------------------------------------------------------
// Kernel 3: merge MLP for pos (src,tgt) and neg (src,bad)
__global__ __launch_bounds__(64) void merge_kernel(
    const float* __restrict__ emb,  const float* __restrict__ fc1_w,
    const float* __restrict__ fc1_b, const float* __restrict__ fc2_w,
    const float* __restrict__ fc2_b, float* __restrict__ out)
{
    __shared__ float se[192];
    const int i = blockIdx.x;
    const int j = threadIdx.x;                    // 0..63
    se[j]       = emb[i * 64 + j];                      // src_e
    se[64 + j]  = emb[(B_SZ + i) * 64 + j];             // tgt_e
    se[128 + j] = emb[(2 * B_SZ + i) * 64 + j];         // bad_e
    __syncthreads();
    const float4* w1 = reinterpret_cast<const float4*>(fc1_w + j * 128);
    float sp = 0.f, tp = 0.f, bp = 0.f;
    #pragma unroll 4
    for (int c = 0; c < 16; ++c) {
        float4 wa = w1[c];
        sp += wa.x * se[c * 4] + wa.y * se[c * 4 + 1] + wa.z * se[c * 4 + 2] + wa.w * se[c * 4 + 3];
        float4 wb = w1[16 + c];
        tp += wb.x * se[64 + c * 4] + wb.y * se[64 + c * 4 + 1] + wb.z * se[64 + c * 4 + 2] + wb.w * se[64 + c * 4 + 3];
        bp += wb.x * se[128 + c * 4] + wb.y * se[128 + c * 4 + 1] + wb.z * se[128 + c * 4 + 2] + wb.w * se[128 + c * 4 + 3];
    }
    const float b1 = fc1_b[j];
    const float w2 = fc2_w[j];
    float p = fmaxf(b1 + sp + tp, 0.f) * w2;
    float n = fmaxf(b1 + sp + bp, 0.f) * w2;
    #pragma unroll
    for (int m = 32; m >= 1; m >>= 1) {
        p += __shfl_xor(p, m, 64);
        n += __shfl_xor(n, m, 64);
    }
    if (j == 0) {
        out[2 * i]     = p + fc2_b[0];
        out[2 * i + 1] = n + fc2_b[0];
    }
}

// ---------------------------------------------------------------------------
extern "C" void kernel_launch(void* const* d_in, const int* in_sizes, int n_in,
                              void* d_out, int out_size, void* d_ws, size_t ws_size,
                              hipStream_t stream) {
    const int*   src_ids  = (const int*)  d_in[0];
    const int*   tgt_ids  = (const int*)  d_in[1];
    const int*   bad_ids  = (const int*)  d_in[2];
    const float* cut_time = (const float*)d_in[3];
    const int*   ngh_id   = (const int*)  d_in[4];
    const int*   e_idx    = (const int*)  d_in[5];
    const float* ngh_ts   = (const float*)d_in[6];
    const float* hidden   = (const float*)d_in[7];
    const float* n_feat   = (const float*)d_in[8];
    const float* e_feat   = (const float*)d_in[9];
    const float* basis    = (const float*)d_in[10];
    const float* phase    = (const float*)d_in[11];
    const float* W_ih     = (const float*)d_in[12];
    const float* W_hh     = (const float*)d_in[13];
    const float* b_ih     = (const float*)d_in[14];
    const float* b_hh     = (const float*)d_in[15];
    const float* W_out    = (const float*)d_in[16];
    const float* b_out    = (const float*)d_in[17];
    const float* fc1_w    = (const float*)d_in[18];
    const float* fc1_b    = (const float*)d_in[19];
    const float* fc2_w    = (const float*)d_in[20];
    const float* fc2_b    = (const float*)d_in[21];

    char* ws = (char*)d_ws;
    short* wihb = (short*)(ws);                       //  98304 B
    short* whhb = (short*)(ws + 98304);               //  98304 B
    float* agg  = (float*)(ws + 196608);              //  12288*128*4 = 6291456 B
    float* emb  = (float*)(ws + 196608 + 6291456);    //  12288*64*4  = 3145728 B
    float* out  = (float*)d_out;

    hipLaunchKernelGGL(prep_kernel, dim3(192), dim3(256), 0, stream, W_ih, W_hh, wihb, whhb);
    hipLaunchKernelGGL(gru_agg_kernel, dim3(6144), dim3(512), 0, stream,
                       ngh_id, e_idx, ngh_ts, hidden, e_feat, basis, phase, cut_time,
                       wihb, whhb, b_ih, b_hh, agg);
    hipLaunchKernelGGL(emb_kernel, dim3(12288), dim3(64), 0, stream,
                       src_ids, tgt_ids, bad_ids, n_feat, W_out, b_out, agg, emb);
    hipLaunchKernelGGL(merge_kernel, dim3(4096), dim3(64), 0, stream,
                       emb, fc1_w, fc1_b, fc2_w, fc2_b, out);
}

// Round 2
// 260.794 us; speedup vs baseline: 1.5500x; 1.5500x over previous
//
#include <hip/hip_runtime.h>
#include <hip/hip_bf16.h>

#define B_SZ   4096
#define F_DIM  64
#define H_DIM  128

typedef short bf16x8 __attribute__((ext_vector_type(8)));
typedef float f32x4  __attribute__((ext_vector_type(4)));

__device__ __forceinline__ short f2bf(float f) {
    __hip_bfloat16 h = __float2bfloat16(f);
    return *reinterpret_cast<short*>(&h);
}
__device__ __forceinline__ float bf2f(unsigned short u) {
    unsigned int x = ((unsigned int)u) << 16;
    float f;
    __builtin_memcpy(&f, &x, 4);
    return f;
}
__device__ __forceinline__ float fsig(float x) {
    return __builtin_amdgcn_rcpf(1.0f + __expf(-x));
}
__device__ __forceinline__ float ftanhf(float x) {
    return 1.0f - 2.0f * __builtin_amdgcn_rcpf(__expf(2.0f * x) + 1.0f);
}
// XOR swizzle for row-major [64][256] bf16 tile (512 B rows): spreads the
// 16B chunks of 8 consecutive rows across all 32 banks (G4 fix).
__device__ __forceinline__ int swz(int row, int cbyte) {
    return row * 512 + (cbyte ^ ((row & 7) << 4));
}

// ---------------------------------------------------------------------------
// Kernel 0: build wcat[384][256] bf16 = [W_ih | W_hh] row-concatenated
__global__ void prep_kernel(const float* __restrict__ wih, const float* __restrict__ whh,
                            short* __restrict__ wcat) {
    int idx = blockIdx.x * 256 + threadIdx.x;     // 384*256 elements
    int r = idx >> 8, c = idx & 255;
    float v = (c < 128) ? wih[r * 128 + c] : whh[r * 128 + (c - 128)];
    wcat[idx] = f2bf(v);
}

// ---------------------------------------------------------------------------
// Kernel 1: fused feature-build + merged GRU GEMM (K=256) + masked mean.
// Block = 2 nodes = 64 rows, 8 waves; wave w owns gate columns [16w,16w+16).
// Gx+Gh merged: r,z accumulate over the full K=256 ([X|H] tile x [Wih|Whh]);
// n gate keeps xn (ks<4) / hn (ks>=4) separate.
__global__ __launch_bounds__(512, 4) void gru_agg_kernel(
    const int*   __restrict__ ngh_id,
    const int*   __restrict__ e_idx,
    const float* __restrict__ ngh_ts,
    const float* __restrict__ hidden_store,
    const float* __restrict__ e_feat,
    const float* __restrict__ basis_freq,
    const float* __restrict__ phase,
    const float* __restrict__ cut_time,
    const short* __restrict__ wcat,
    const float* __restrict__ b_ih,
    const float* __restrict__ b_hh,
    float*       __restrict__ agg)
{
    __shared__ __align__(16) char sT[64 * 512];   // 64 rows x 256 bf16 cols, swizzled
    __shared__ float sMask[64];
    __shared__ float sInv[2];

    const int bid = blockIdx.x;
    const int tid = threadIdx.x;

    // ---- stage [e_emb | ts_emb | h] -> bf16 LDS tile ----
    {
        const int row   = tid >> 3;          // 0..63
        const int q     = tid & 7;           // 32 cols each
        const int flat  = bid * 64 + row;
        const int rnode = bid * 2 + (row >> 5);

        float vals[32];
        if (q < 2) {                         // e_emb cols q*32..+32
            const int e = e_idx[flat];
            const float4* src = reinterpret_cast<const float4*>(e_feat + (size_t)e * F_DIM + q * 32);
            #pragma unroll
            for (int t = 0; t < 8; ++t) *reinterpret_cast<float4*>(&vals[t * 4]) = src[t];
        } else if (q < 4) {                  // ts_emb
            const float dt = cut_time[rnode & (B_SZ - 1)] - ngh_ts[flat];
            const int f0 = (q - 2) * 32;
            #pragma unroll
            for (int i = 0; i < 32; ++i)
                vals[i] = __cosf(dt * basis_freq[f0 + i] + phase[f0 + i]);
        } else {                             // h cols (q-4)*32..+32
            const float4* src = reinterpret_cast<const float4*>(hidden_store + (size_t)flat * H_DIM + (q - 4) * 32);
            #pragma unroll
            for (int t = 0; t < 8; ++t) *reinterpret_cast<float4*>(&vals[t * 4]) = src[t];
        }
        union { bf16x8 v[4]; short s[32]; } u;
        #pragma unroll
        for (int i = 0; i < 32; ++i) u.s[i] = f2bf(vals[i]);
        const int cb = q * 64;
        #pragma unroll
        for (int t = 0; t < 4; ++t)
            *reinterpret_cast<bf16x8*>(&sT[swz(row, cb + t * 16)]) = u.v[t];

        if (tid < 64) {                      // mask + neighbor counts (wave 0)
            const int nid = ngh_id[bid * 64 + tid];
            sMask[tid] = (nid != 0) ? 1.0f : 0.0f;
            unsigned long long mb = __ballot(nid != 0);
            if (tid == 0) {
                int c0n = __popcll(mb & 0xFFFFFFFFull);
                int c1n = __popcll(mb >> 32);
                sInv[0] = 1.0f / (float)(c0n > 1 ? c0n : 1);
                sInv[1] = 1.0f / (float)(c1n > 1 ? c1n : 1);
            }
        }
    }
    __syncthreads();

    // ---- K-loop: K=256 merged GEMM ----
    const int lane = tid & 63;
    const int wv   = tid >> 6;           // 0..7
    const int jc   = wv * 16 + (lane & 15);
    const int kh   = lane >> 4;          // 0..3

    f32x4 ar[4], az[4], axn[4], ahn[4];
    #pragma unroll
    for (int mf = 0; mf < 4; ++mf) {
        ar[mf]  = (f32x4){0.f, 0.f, 0.f, 0.f};
        az[mf]  = (f32x4){0.f, 0.f, 0.f, 0.f};
        axn[mf] = (f32x4){0.f, 0.f, 0.f, 0.f};
        ahn[mf] = (f32x4){0.f, 0.f, 0.f, 0.f};
    }

    const short* wr_r = wcat + (size_t)jc * 256;
    const short* wr_z = wcat + (size_t)(128 + jc) * 256;
    const short* wr_n = wcat + (size_t)(256 + jc) * 256;

    #pragma unroll
    for (int ks = 0; ks < 8; ++ks) {
        bf16x8 a[4];
        #pragma unroll
        for (int mf = 0; mf < 4; ++mf)
            a[mf] = *reinterpret_cast<const bf16x8*>(&sT[swz(mf * 16 + (lane & 15), ks * 64 + kh * 16)]);
        const int ko = ks * 32 + kh * 8;
        bf16x8 br = *reinterpret_cast<const bf16x8*>(wr_r + ko);
        bf16x8 bz = *reinterpret_cast<const bf16x8*>(wr_z + ko);
        bf16x8 bn = *reinterpret_cast<const bf16x8*>(wr_n + ko);
        #pragma unroll
        for (int mf = 0; mf < 4; ++mf)
            ar[mf] = __builtin_amdgcn_mfma_f32_16x16x32_bf16(a[mf], br, ar[mf], 0, 0, 0);
        #pragma unroll
        for (int mf = 0; mf < 4; ++mf)
            az[mf] = __builtin_amdgcn_mfma_f32_16x16x32_bf16(a[mf], bz, az[mf], 0, 0, 0);
        if (ks < 4) {
            #pragma unroll
            for (int mf = 0; mf < 4; ++mf)
                axn[mf] = __builtin_amdgcn_mfma_f32_16x16x32_bf16(a[mf], bn, axn[mf], 0, 0, 0);
        } else {
            #pragma unroll
            for (int mf = 0; mf < 4; ++mf)
                ahn[mf] = __builtin_amdgcn_mfma_f32_16x16x32_bf16(a[mf], bn, ahn[mf], 0, 0, 0);
        }
    }

    // ---- epilogue: gates, h_new, masked sum over K, mean ----
    const float brz = b_ih[jc] + b_hh[jc];
    const float bzz = b_ih[128 + jc] + b_hh[128 + jc];
    const float bin = b_ih[256 + jc];
    const float bhn = b_hh[256 + jc];

    float s0 = 0.f, s1 = 0.f;
    #pragma unroll
    for (int mf = 0; mf < 4; ++mf) {
        #pragma unroll
        for (int i = 0; i < 4; ++i) {
            const int row = mf * 16 + kh * 4 + i;     // C/D: col=lane&15, row=kh*4+i
            const float rr = fsig(ar[mf][i] + brz);
            const float zz = fsig(az[mf][i] + bzz);
            const float nn = ftanhf(axn[mf][i] + bin + rr * (ahn[mf][i] + bhn));
            const float hc = bf2f(*reinterpret_cast<const unsigned short*>(&sT[swz(row, 256 + jc * 2)]));
            const float hv = ((1.0f - zz) * nn + zz * hc) * sMask[row];
            if (mf < 2) s0 += hv; else s1 += hv;
        }
    }
    s0 += __shfl_xor(s0, 16, 64);
    s0 += __shfl_xor(s0, 32, 64);
    s1 += __shfl_xor(s1, 16, 64);
    s1 += __shfl_xor(s1, 32, 64);
    if (lane < 16) {
        agg[(bid * 2 + 0) * H_DIM + jc] = s0 * sInv[0];
        agg[(bid * 2 + 1) * H_DIM + jc] = s1 * sInv[1];
    }
}

// ---------------------------------------------------------------------------
// Kernel 2: emb = relu([node_raw, agg] @ W_out^T + b_out); 16 nodes/block
__global__ __launch_bounds__(256) void emb_kernel(
    const int*   __restrict__ src_ids, const int* __restrict__ tgt_ids,
    const int*   __restrict__ bad_ids, const float* __restrict__ n_feat,
    const float* __restrict__ W_out,   const float* __restrict__ b_out,
    const float* __restrict__ agg,     float* __restrict__ emb)
{
    __shared__ float sv[16][192];
    const int base = blockIdx.x * 16;
    const int j  = threadIdx.x & 63;
    const int ng = threadIdx.x >> 6;              // 0..3 -> nodes ng*4..+4
    #pragma unroll
    for (int n0 = 0; n0 < 4; ++n0) {
        const int n = ng * 4 + n0;
        const int node = base + n;
        int id;
        if (node < B_SZ)          id = src_ids[node];
        else if (node < 2 * B_SZ) id = tgt_ids[node - B_SZ];
        else                      id = bad_ids[node - 2 * B_SZ];
        sv[n][j]       = n_feat[(size_t)id * F_DIM + j];
        sv[n][64 + j]  = agg[(size_t)node * H_DIM + j];
        sv[n][128 + j] = agg[(size_t)node * H_DIM + 64 + j];
    }
    __syncthreads();
    float acc[4];
    const float bj = b_out[j];
    #pragma unroll
    for (int n0 = 0; n0 < 4; ++n0) acc[n0] = bj;
    const float4* wr = reinterpret_cast<const float4*>(W_out + j * 192);
    #pragma unroll 4
    for (int c = 0; c < 48; ++c) {
        float4 w = wr[c];
        #pragma unroll
        for (int n0 = 0; n0 < 4; ++n0) {
            const float* s = &sv[ng * 4 + n0][c * 4];
            acc[n0] += w.x * s[0] + w.y * s[1] + w.z * s[2] + w.w * s[3];
        }
    }
    #pragma unroll
    for (int n0 = 0; n0 < 4; ++n0)
        emb[(size_t)(base + ng * 4 + n0) * F_DIM + j] = fmaxf(acc[n0], 0.0f);
}

// ---------------------------------------------------------------------------
// Kernel 3: merge MLP; 16 pairs/block
__global__ __launch_bounds__(256) void merge_kernel(
    const float* __restrict__ emb,  const float* __restrict__ fc1_w,
    const float* __restrict__ fc1_b, const float* __restrict__ fc2_w,
    const float* __restrict__ fc2_b, float* __restrict__ out)
{
    __shared__ float se[16][192];
    const int base = blockIdx.x * 16;
    const int j  = threadIdx.x & 63;
    const int ng = threadIdx.x >> 6;
    #pragma unroll
    for (int p0 = 0; p0 < 4; ++p0) {
        const int p = ng * 4 + p0;
        const int i = base + p;
        se[p][j]       = emb[(size_t)i * 64 + j];
        se[p][64 + j]  = emb[(size_t)(B_SZ + i) * 64 + j];
        se[p][128 + j] = emb[(size_t)(2 * B_SZ + i) * 64 + j];
    }
    __syncthreads();
    const float4* w1 = reinterpret_cast<const float4*>(fc1_w + j * 128);
    float sp[4] = {0, 0, 0, 0}, tp[4] = {0, 0, 0, 0}, bp[4] = {0, 0, 0, 0};
    #pragma unroll 4
    for (int c = 0; c < 16; ++c) {
        float4 wa = w1[c];
        float4 wb = w1[16 + c];
        #pragma unroll
        for (int p0 = 0; p0 < 4; ++p0) {
            const float* s = se[ng * 4 + p0];
            const float* sa = &s[c * 4];
            sp[p0] += wa.x * sa[0] + wa.y * sa[1] + wa.z * sa[2] + wa.w * sa[3];
            const float* st = &s[64 + c * 4];
            tp[p0] += wb.x * st[0] + wb.y * st[1] + wb.z * st[2] + wb.w * st[3];
            const float* sb = &s[128 + c * 4];
            bp[p0] += wb.x * sb[0] + wb.y * sb[1] + wb.z * sb[2] + wb.w * sb[3];
        }
    }
    const float b1 = fc1_b[j];
    const float w2 = fc2_w[j];
    #pragma unroll
    for (int p0 = 0; p0 < 4; ++p0) {
        float p = fmaxf(b1 + sp[p0] + tp[p0], 0.f) * w2;
        float n = fmaxf(b1 + sp[p0] + bp[p0], 0.f) * w2;
        #pragma unroll
        for (int m = 32; m >= 1; m >>= 1) {
            p += __shfl_xor(p, m, 64);
            n += __shfl_xor(n, m, 64);
        }
        if (j == 0) {
            const int i = base + ng * 4 + p0;
            out[2 * i]     = p + fc2_b[0];
            out[2 * i + 1] = n + fc2_b[0];
        }
    }
}

// ---------------------------------------------------------------------------
extern "C" void kernel_launch(void* const* d_in, const int* in_sizes, int n_in,
                              void* d_out, int out_size, void* d_ws, size_t ws_size,
                              hipStream_t stream) {
    const int*   src_ids  = (const int*)  d_in[0];
    const int*   tgt_ids  = (const int*)  d_in[1];
    const int*   bad_ids  = (const int*)  d_in[2];
    const float* cut_time = (const float*)d_in[3];
    const int*   ngh_id   = (const int*)  d_in[4];
    const int*   e_idx    = (const int*)  d_in[5];
    const float* ngh_ts   = (const float*)d_in[6];
    const float* hidden   = (const float*)d_in[7];
    const float* n_feat   = (const float*)d_in[8];
    const float* e_feat   = (const float*)d_in[9];
    const float* basis    = (const float*)d_in[10];
    const float* phase    = (const float*)d_in[11];
    const float* W_ih     = (const float*)d_in[12];
    const float* W_hh     = (const float*)d_in[13];
    const float* b_ih     = (const float*)d_in[14];
    const float* b_hh     = (const float*)d_in[15];
    const float* W_out    = (const float*)d_in[16];
    const float* b_out    = (const float*)d_in[17];
    const float* fc1_w    = (const float*)d_in[18];
    const float* fc1_b    = (const float*)d_in[19];
    const float* fc2_w    = (const float*)d_in[20];
    const float* fc2_b    = (const float*)d_in[21];

    char* ws = (char*)d_ws;
    short* wcat = (short*)(ws);                        // 384*256*2 = 196608 B
    float* agg  = (float*)(ws + 196608);               // 12288*128*4 = 6291456 B
    float* emb  = (float*)(ws + 196608 + 6291456);     // 12288*64*4  = 3145728 B
    float* out  = (float*)d_out;

    hipLaunchKernelGGL(prep_kernel, dim3(384), dim3(256), 0, stream, W_ih, W_hh, wcat);
    hipLaunchKernelGGL(gru_agg_kernel, dim3(6144), dim3(512), 0, stream,
                       ngh_id, e_idx, ngh_ts, hidden, e_feat, basis, phase, cut_time,
                       wcat, b_ih, b_hh, agg);
    hipLaunchKernelGGL(emb_kernel, dim3(768), dim3(256), 0, stream,
                       src_ids, tgt_ids, bad_ids, n_feat, W_out, b_out, agg, emb);
    hipLaunchKernelGGL(merge_kernel, dim3(256), dim3(256), 0, stream,
                       emb, fc1_w, fc1_b, fc2_w, fc2_b, out);
}

// Round 4
// 181.616 us; speedup vs baseline: 2.2257x; 1.4360x over previous
//
#include <hip/hip_runtime.h>
#include <hip/hip_bf16.h>

#define B_SZ   4096

typedef short bf16x8 __attribute__((ext_vector_type(8)));
typedef float f32x4  __attribute__((ext_vector_type(4)));

__device__ __forceinline__ short f2bf(float f) {
    __hip_bfloat16 h = __float2bfloat16(f);
    return *reinterpret_cast<short*>(&h);
}
__device__ __forceinline__ float bf2f(unsigned int u16) {
    unsigned int x = u16 << 16;
    float f;
    __builtin_memcpy(&f, &x, 4);
    return f;
}
__device__ __forceinline__ float fsig(float x) {
    return __builtin_amdgcn_rcpf(1.0f + __expf(-x));
}
__device__ __forceinline__ float ftanhf(float x) {
    return 1.0f - 2.0f * __builtin_amdgcn_rcpf(__expf(2.0f * x) + 1.0f);
}
// XOR swizzle for row-major [64][256] bf16 tile (512 B rows)
__device__ __forceinline__ int swz(int row, int cbyte) {
    return row * 512 + (cbyte ^ ((row & 7) << 4));
}

// ---------------------------------------------------------------------------
// Kernel 0: weights -> fragment-major bf16 layout wfrag[g][ks][j][kh][8]
// so each wave's B-fragment load is one fully-coalesced 1KB burst.
__global__ void prep_kernel(const float* __restrict__ wih, const float* __restrict__ whh,
                            short* __restrict__ wfrag) {
    int idx = blockIdx.x * 256 + threadIdx.x;     // 3*8*128*4*8 = 98304
    int i   = idx & 7;
    int kh  = (idx >> 3) & 3;
    int j   = (idx >> 5) & 127;
    int gks = idx >> 12;                          // g*8+ks
    int g   = gks >> 3, ks = gks & 7;
    int k   = ks * 32 + kh * 8 + i;
    int r   = g * 128 + j;
    float v = (k < 128) ? wih[r * 128 + k] : whh[r * 128 + (k - 128)];
    wfrag[idx] = f2bf(v);
}

// ---------------------------------------------------------------------------
// Kernel 1: fused feature-build + merged GRU GEMM (K=256) + masked mean.
// Block = 2 nodes = 64 rows, 8 waves. Staging is WAVE-SPECIALIZED:
// waves 0-1: e_feat gather; waves 2-3: cos(ts) + mask; waves 4-7: hidden copy.
// GEMM/numerics path identical to the verified round-1 kernel (scalar RNE
// f2bf, plain-float gates) — only staging assignment and weight layout moved.
__global__ __launch_bounds__(512, 4) void gru_agg_kernel(
    const int*   __restrict__ ngh_id,
    const int*   __restrict__ e_idx,
    const float* __restrict__ ngh_ts,
    const float* __restrict__ hidden_store,
    const float* __restrict__ e_feat,
    const float* __restrict__ basis_freq,
    const float* __restrict__ phase,
    const float* __restrict__ cut_time,
    const short* __restrict__ wfrag,
    const float* __restrict__ b_ih,
    const float* __restrict__ b_hh,
    float*       __restrict__ agg)
{
    __shared__ __align__(16) char sT[64 * 512];   // [64 rows][256 bf16 cols] swizzled
    __shared__ float sMask[64];
    __shared__ float sInv[2];

    const int bid  = blockIdx.x;
    const int tid  = threadIdx.x;
    const int lane = tid & 63;
    const int wv   = tid >> 6;

    // ---- wave-specialized staging ----
    if (wv < 2) {                                 // e_emb: wave0 cols 0-31, wave1 32-63
        const int row  = lane;
        const int flat = bid * 64 + row;
        const int e    = e_idx[flat];
        const float4* src = reinterpret_cast<const float4*>(e_feat + (size_t)e * 64 + wv * 32);
        float v[32];
        #pragma unroll
        for (int t = 0; t < 8; ++t) *reinterpret_cast<float4*>(&v[t * 4]) = src[t];
        union { bf16x8 w[4]; short s[32]; } u;
        #pragma unroll
        for (int i = 0; i < 32; ++i) u.s[i] = f2bf(v[i]);
        const int cb = wv * 64;
        #pragma unroll
        for (int t = 0; t < 4; ++t)
            *reinterpret_cast<bf16x8*>(&sT[swz(row, cb + t * 16)]) = u.w[t];
    } else if (wv < 4) {                          // ts_emb + (wave2) mask/counts
        const int row  = lane;
        const int flat = bid * 64 + row;
        if (wv == 2) {
            const int nid = ngh_id[flat];
            sMask[row] = (nid != 0) ? 1.0f : 0.0f;
            unsigned long long mb = __ballot(nid != 0);
            if (lane == 0) {
                int c0n = __popcll(mb & 0xFFFFFFFFull);
                int c1n = __popcll(mb >> 32);
                sInv[0] = 1.0f / (float)(c0n > 1 ? c0n : 1);
                sInv[1] = 1.0f / (float)(c1n > 1 ? c1n : 1);
            }
        }
        const int rnode = bid * 2 + (row >> 5);
        const float dt  = cut_time[rnode & (B_SZ - 1)] - ngh_ts[flat];
        const int f0 = (wv - 2) * 32;
        float v[32];
        #pragma unroll
        for (int i = 0; i < 32; ++i)
            v[i] = __cosf(dt * basis_freq[f0 + i] + phase[f0 + i]);
        union { bf16x8 w[4]; short s[32]; } u;
        #pragma unroll
        for (int i = 0; i < 32; ++i) u.s[i] = f2bf(v[i]);
        const int cb = 128 + f0 * 2;
        #pragma unroll
        for (int t = 0; t < 4; ++t)
            *reinterpret_cast<bf16x8*>(&sT[swz(row, cb + t * 16)]) = u.w[t];
    } else {                                      // hidden: wave 4+hw rows hw*16..+16
        const int hw   = wv - 4;
        const int row  = hw * 16 + (lane >> 2);
        const int flat = bid * 64 + row;
        const int c0   = (lane & 3) * 32;
        const float4* src = reinterpret_cast<const float4*>(hidden_store + (size_t)flat * 128 + c0);
        float v[32];
        #pragma unroll
        for (int t = 0; t < 8; ++t) *reinterpret_cast<float4*>(&v[t * 4]) = src[t];
        union { bf16x8 w[4]; short s[32]; } u;
        #pragma unroll
        for (int i = 0; i < 32; ++i) u.s[i] = f2bf(v[i]);
        const int cb = 256 + c0 * 2;
        #pragma unroll
        for (int t = 0; t < 4; ++t)
            *reinterpret_cast<bf16x8*>(&sT[swz(row, cb + t * 16)]) = u.w[t];
    }
    __syncthreads();

    // ---- K-loop: K=256 merged GEMM (single pass, round-1 dataflow) ----
    const int l15 = lane & 15;
    const int kh  = lane >> 4;
    const int jc  = (wv << 4) + l15;

    f32x4 ar[4], az[4], axn[4], ahn[4];
    #pragma unroll
    for (int mf = 0; mf < 4; ++mf) {
        ar[mf]  = (f32x4){0.f, 0.f, 0.f, 0.f};
        az[mf]  = (f32x4){0.f, 0.f, 0.f, 0.f};
        axn[mf] = (f32x4){0.f, 0.f, 0.f, 0.f};
        ahn[mf] = (f32x4){0.f, 0.f, 0.f, 0.f};
    }

    #pragma unroll
    for (int ks = 0; ks < 8; ++ks) {
        bf16x8 a[4];
        #pragma unroll
        for (int mf = 0; mf < 4; ++mf)
            a[mf] = *reinterpret_cast<const bf16x8*>(&sT[swz(mf * 16 + l15, ks * 64 + kh * 16)]);
        bf16x8 br = *reinterpret_cast<const bf16x8*>(wfrag + (((((0 * 8 + ks) * 128 + jc) << 2) + kh) << 3));
        bf16x8 bz = *reinterpret_cast<const bf16x8*>(wfrag + (((((1 * 8 + ks) * 128 + jc) << 2) + kh) << 3));
        bf16x8 bn = *reinterpret_cast<const bf16x8*>(wfrag + (((((2 * 8 + ks) * 128 + jc) << 2) + kh) << 3));
        #pragma unroll
        for (int mf = 0; mf < 4; ++mf)
            ar[mf] = __builtin_amdgcn_mfma_f32_16x16x32_bf16(a[mf], br, ar[mf], 0, 0, 0);
        #pragma unroll
        for (int mf = 0; mf < 4; ++mf)
            az[mf] = __builtin_amdgcn_mfma_f32_16x16x32_bf16(a[mf], bz, az[mf], 0, 0, 0);
        if (ks < 4) {
            #pragma unroll
            for (int mf = 0; mf < 4; ++mf)
                axn[mf] = __builtin_amdgcn_mfma_f32_16x16x32_bf16(a[mf], bn, axn[mf], 0, 0, 0);
        } else {
            #pragma unroll
            for (int mf = 0; mf < 4; ++mf)
                ahn[mf] = __builtin_amdgcn_mfma_f32_16x16x32_bf16(a[mf], bn, ahn[mf], 0, 0, 0);
        }
    }

    // ---- epilogue: gates, h_new, masked sum over K, mean ----
    const float brz = b_ih[jc] + b_hh[jc];
    const float bzz = b_ih[128 + jc] + b_hh[128 + jc];
    const float bin = b_ih[256 + jc];
    const float bhn = b_hh[256 + jc];

    float s0 = 0.f, s1 = 0.f;
    #pragma unroll
    for (int mf = 0; mf < 4; ++mf) {
        #pragma unroll
        for (int i = 0; i < 4; ++i) {
            const int row = mf * 16 + kh * 4 + i;     // C/D: col=lane&15, row=kh*4+i
            const float rr = fsig(ar[mf][i] + brz);
            const float zz = fsig(az[mf][i] + bzz);
            const float nn = ftanhf(axn[mf][i] + bin + rr * (ahn[mf][i] + bhn));
            const float hc = bf2f(*reinterpret_cast<const unsigned short*>(&sT[swz(row, 256 + jc * 2)]));
            const float hv = ((1.0f - zz) * nn + zz * hc) * sMask[row];
            if (mf < 2) s0 += hv; else s1 += hv;
        }
    }
    s0 += __shfl_xor(s0, 16, 64);
    s0 += __shfl_xor(s0, 32, 64);
    s1 += __shfl_xor(s1, 16, 64);
    s1 += __shfl_xor(s1, 32, 64);
    if (lane < 16) {
        agg[(bid * 2 + 0) * 128 + jc] = s0 * sInv[0];
        agg[(bid * 2 + 1) * 128 + jc] = s1 * sInv[1];
    }
}

// ---------------------------------------------------------------------------
// Kernel 2: emb = relu([node_raw, agg] @ W_out^T + b_out); 16 nodes/block
__global__ __launch_bounds__(256) void emb_kernel(
    const int*   __restrict__ src_ids, const int* __restrict__ tgt_ids,
    const int*   __restrict__ bad_ids, const float* __restrict__ n_feat,
    const float* __restrict__ W_out,   const float* __restrict__ b_out,
    const float* __restrict__ agg,     float* __restrict__ emb)
{
    __shared__ float sv[16][192];
    const int base = blockIdx.x * 16;
    const int j  = threadIdx.x & 63;
    const int ng = threadIdx.x >> 6;
    #pragma unroll
    for (int n0 = 0; n0 < 4; ++n0) {
        const int n = ng * 4 + n0;
        const int node = base + n;
        int id;
        if (node < B_SZ)          id = src_ids[node];
        else if (node < 2 * B_SZ) id = tgt_ids[node - B_SZ];
        else                      id = bad_ids[node - 2 * B_SZ];
        sv[n][j]       = n_feat[(size_t)id * 64 + j];
        sv[n][64 + j]  = agg[(size_t)node * 128 + j];
        sv[n][128 + j] = agg[(size_t)node * 128 + 64 + j];
    }
    __syncthreads();
    float acc[4];
    const float bj = b_out[j];
    #pragma unroll
    for (int n0 = 0; n0 < 4; ++n0) acc[n0] = bj;
    const float4* wr = reinterpret_cast<const float4*>(W_out + j * 192);
    #pragma unroll 4
    for (int c = 0; c < 48; ++c) {
        float4 w = wr[c];
        #pragma unroll
        for (int n0 = 0; n0 < 4; ++n0) {
            const float* s = &sv[ng * 4 + n0][c * 4];
            acc[n0] += w.x * s[0] + w.y * s[1] + w.z * s[2] + w.w * s[3];
        }
    }
    #pragma unroll
    for (int n0 = 0; n0 < 4; ++n0)
        emb[(size_t)(base + ng * 4 + n0) * 64 + j] = fmaxf(acc[n0], 0.0f);
}

// ---------------------------------------------------------------------------
// Kernel 3: merge MLP; 16 pairs/block
__global__ __launch_bounds__(256) void merge_kernel(
    const float* __restrict__ emb,  const float* __restrict__ fc1_w,
    const float* __restrict__ fc1_b, const float* __restrict__ fc2_w,
    const float* __restrict__ fc2_b, float* __restrict__ out)
{
    __shared__ float se[16][192];
    const int base = blockIdx.x * 16;
    const int j  = threadIdx.x & 63;
    const int ng = threadIdx.x >> 6;
    #pragma unroll
    for (int p0 = 0; p0 < 4; ++p0) {
        const int p = ng * 4 + p0;
        const int i = base + p;
        se[p][j]       = emb[(size_t)i * 64 + j];
        se[p][64 + j]  = emb[(size_t)(B_SZ + i) * 64 + j];
        se[p][128 + j] = emb[(size_t)(2 * B_SZ + i) * 64 + j];
    }
    __syncthreads();
    const float4* w1 = reinterpret_cast<const float4*>(fc1_w + j * 128);
    float sp[4] = {0, 0, 0, 0}, tp[4] = {0, 0, 0, 0}, bp[4] = {0, 0, 0, 0};
    #pragma unroll 4
    for (int c = 0; c < 16; ++c) {
        float4 wa = w1[c];
        float4 wb = w1[16 + c];
        #pragma unroll
        for (int p0 = 0; p0 < 4; ++p0) {
            const float* s = se[ng * 4 + p0];
            const float* sa = &s[c * 4];
            sp[p0] += wa.x * sa[0] + wa.y * sa[1] + wa.z * sa[2] + wa.w * sa[3];
            const float* st = &s[64 + c * 4];
            tp[p0] += wb.x * st[0] + wb.y * st[1] + wb.z * st[2] + wb.w * st[3];
            const float* sb = &s[128 + c * 4];
            bp[p0] += wb.x * sb[0] + wb.y * sb[1] + wb.z * sb[2] + wb.w * sb[3];
        }
    }
    const float b1 = fc1_b[j];
    const float w2 = fc2_w[j];
    #pragma unroll
    for (int p0 = 0; p0 < 4; ++p0) {
        float p = fmaxf(b1 + sp[p0] + tp[p0], 0.f) * w2;
        float n = fmaxf(b1 + sp[p0] + bp[p0], 0.f) * w2;
        #pragma unroll
        for (int m = 32; m >= 1; m >>= 1) {
            p += __shfl_xor(p, m, 64);
            n += __shfl_xor(n, m, 64);
        }
        if (j == 0) {
            const int i = base + ng * 4 + p0;
            out[2 * i]     = p + fc2_b[0];
            out[2 * i + 1] = n + fc2_b[0];
        }
    }
}

// ---------------------------------------------------------------------------
extern "C" void kernel_launch(void* const* d_in, const int* in_sizes, int n_in,
                              void* d_out, int out_size, void* d_ws, size_t ws_size,
                              hipStream_t stream) {
    const int*   src_ids  = (const int*)  d_in[0];
    const int*   tgt_ids  = (const int*)  d_in[1];
    const int*   bad_ids  = (const int*)  d_in[2];
    const float* cut_time = (const float*)d_in[3];
    const int*   ngh_id   = (const int*)  d_in[4];
    const int*   e_idx    = (const int*)  d_in[5];
    const float* ngh_ts   = (const float*)d_in[6];
    const float* hidden   = (const float*)d_in[7];
    const float* n_feat   = (const float*)d_in[8];
    const float* e_feat   = (const float*)d_in[9];
    const float* basis    = (const float*)d_in[10];
    const float* phase    = (const float*)d_in[11];
    const float* W_ih     = (const float*)d_in[12];
    const float* W_hh     = (const float*)d_in[13];
    const float* b_ih     = (const float*)d_in[14];
    const float* b_hh     = (const float*)d_in[15];
    const float* W_out    = (const float*)d_in[16];
    const float* b_out    = (const float*)d_in[17];
    const float* fc1_w    = (const float*)d_in[18];
    const float* fc1_b    = (const float*)d_in[19];
    const float* fc2_w    = (const float*)d_in[20];
    const float* fc2_b    = (const float*)d_in[21];

    char* ws = (char*)d_ws;
    short* wfrag = (short*)(ws);                       // 98304*2 = 196608 B
    float* agg   = (float*)(ws + 196608);              // 12288*128*4 = 6291456 B
    float* emb   = (float*)(ws + 196608 + 6291456);    // 12288*64*4  = 3145728 B
    float* out   = (float*)d_out;

    hipLaunchKernelGGL(prep_kernel, dim3(384), dim3(256), 0, stream, W_ih, W_hh, wfrag);
    hipLaunchKernelGGL(gru_agg_kernel, dim3(6144), dim3(512), 0, stream,
                       ngh_id, e_idx, ngh_ts, hidden, e_feat, basis, phase, cut_time,
                       wfrag, b_ih, b_hh, agg);
    hipLaunchKernelGGL(emb_kernel, dim3(768), dim3(256), 0, stream,
                       src_ids, tgt_ids, bad_ids, n_feat, W_out, b_out, agg, emb);
    hipLaunchKernelGGL(merge_kernel, dim3(256), dim3(256), 0, stream,
                       emb, fc1_w, fc1_b, fc2_w, fc2_b, out);
}